// Round 12
// baseline (253.108 us; speedup 1.0000x reference)
//
#include <hip/hip_runtime.h>

typedef unsigned short ushort_t;
typedef __attribute__((ext_vector_type(4))) float f32x4;
typedef __attribute__((ext_vector_type(8))) short s16x8;
typedef __attribute__((ext_vector_type(8))) unsigned short u16x8;

#define NNODE 2592
#define MATSZ (512*512)
#define INV53 (1.0f/(53.0f + 1e-8f))

__device__ __forceinline__ ushort_t f2b(float f){
  union {unsigned int i; float f;} x; x.f = f;
  unsigned int r = (x.i + 0x7fffu + ((x.i>>16)&1u))>>16;
  return (ushort_t)r;
}

// ---------------------------------------------------------------------------
// gemm32 (verified): 32-row x 128-col tile, barrier-free K-loop.
// A in swizzled LDS (32x512 bf16); B streamed global->reg from WT[n][k].
// C/D: row = mf*16 + quad*4 + r, col = wave*32 + nf*16 + ml.
// ---------------------------------------------------------------------------
__device__ __forceinline__ void gemm32(const ushort_t* As,
    const ushort_t* W, int col0, f32x4 acc[2][2])
{
  const int tid = threadIdx.x;
  const int wave = tid>>6, lane = tid&63;
  const int ml = lane&15, quad = lane>>4;
  #pragma unroll
  for (int mf=0;mf<2;mf++)
    #pragma unroll
    for (int nf=0;nf<2;nf++) acc[mf][nf] = (f32x4){0.f,0.f,0.f,0.f};

  const ushort_t* bw0 = W + (size_t)(col0 + wave*32 + ml)*512 + quad*8;
  const ushort_t* bw1 = bw0 + (size_t)16*512;
  const int rsw = ml&7;
  #pragma unroll
  for (int ks=0; ks<16; ks++){
    const int chunk = ks*4 + quad;
    const int abase = (chunk>>3)*64 + (((chunk&7) ^ rsw)<<3);
    s16x8 a0 = *(const s16x8*)&As[(size_t)ml*512 + abase];
    s16x8 a1 = *(const s16x8*)&As[(size_t)(16+ml)*512 + abase];
    s16x8 b0 = *(const s16x8*)(bw0 + ks*32);
    s16x8 b1 = *(const s16x8*)(bw1 + ks*32);
    acc[0][0] = __builtin_amdgcn_mfma_f32_16x16x32_bf16(a0,b0,acc[0][0],0,0,0);
    acc[0][1] = __builtin_amdgcn_mfma_f32_16x16x32_bf16(a0,b1,acc[0][1],0,0,0);
    acc[1][0] = __builtin_amdgcn_mfma_f32_16x16x32_bf16(a1,b0,acc[1][0],0,0,0);
    acc[1][1] = __builtin_amdgcn_mfma_f32_16x16x32_bf16(a1,b1,acc[1][1],0,0,0);
  }
}

// stage 32 contiguous fp32 rows of a [*,512] matrix into swizzled bf16 LDS
__device__ __forceinline__ void stageA_flat(ushort_t* As, const float* src, int r0){
  const int tid = threadIdx.x;
  int row = tid>>3, seg = tid&7;
  const float* p = src + (size_t)(r0+row)*512 + seg*64;
  int rsw = row&7;
  ushort_t* dstA = &As[row*512 + seg*64];
  #pragma unroll
  for (int j=0;j<8;j++){
    f32x4 xa = *(const f32x4*)(p+j*8), xb = *(const f32x4*)(p+j*8+4);
    u16x8 v;
    #pragma unroll
    for (int jj=0;jj<4;jj++){ v[jj]=f2b(xa[jj]); v[4+jj]=f2b(xb[jj]); }
    *(u16x8*)&dstA[(j ^ rsw)<<3] = v;
  }
}

// vectorized 64x64 transpose tile: fp32 [k][n] -> bf16 dst[n][k]
__device__ __forceinline__ void transpose_tile(float (*tile)[65],
    const float* src, const float* src2, ushort_t* dst, int bx, int by)
{
  const int tid = threadIdx.x;
  int r0 = bx*64, c0 = by*64;
  #pragma unroll
  for (int j=0;j<4;j++){
    int idx = j*256 + tid;
    int r = idx>>4, c4 = (idx&15)*4;
    size_t off = (size_t)(r0+r)*512 + c0 + c4;
    f32x4 v = *(const f32x4*)&src[off];
    if (src2){
      f32x4 v2 = *(const f32x4*)&src2[off];
      #pragma unroll
      for (int jj=0;jj<4;jj++) v[jj] -= INV53 * v2[jj];
    }
    #pragma unroll
    for (int jj=0;jj<4;jj++) tile[r][c4+jj] = v[jj];
  }
  __syncthreads();
  #pragma unroll
  for (int j=0;j<2;j++){
    int idx = j*256 + tid;
    int c = idx>>3, r8 = (idx&7)*8;
    u16x8 v;
    #pragma unroll
    for (int tt=0;tt<8;tt++) v[tt] = f2b(tile[r8+tt][c]);
    *(u16x8*)&dst[(size_t)(c0+c)*512 + r0 + r8] = v;
  }
}

// ---------------------------------------------------------------------------
// prep0: blocks [0,48): FS[(d,m)] per-speaker feature sums (2-way interleave);
//        blocks [48,112): transpose slot 0 (fc1_W).  Block 0 inits acc/counter.
// ---------------------------------------------------------------------------
__global__ __launch_bounds__(256) void prep0_kernel(
    const float* __restrict__ fc1,
    const float* __restrict__ A_in, const float* __restrict__ V_in,
    const float* __restrict__ L_in, const float* __restrict__ qmask,
    const float* __restrict__ spk,
    ushort_t* __restrict__ WT, float* __restrict__ FS,
    float* __restrict__ cnts, float* __restrict__ acc,
    unsigned int* __restrict__ counter)
{
  __shared__ float tile[64][65];
  __shared__ unsigned char spks[54];
  const int tid = threadIdx.x;
  if (blockIdx.x < 48){
    if (blockIdx.x==0 && tid==0){ *acc = 0.f; *counter = 0u; }
    const int d = blockIdx.x/3, m = blockIdx.x - d*3;
    if (tid < 54)
      spks[tid] = qmask[(tid*16+d)*2+1] > qmask[(tid*16+d)*2];
    __syncthreads();
    float cnt1 = 0.f;
    #pragma unroll
    for (int i=0;i<54;i++) cnt1 += (float)spks[i];
    float cnt0 = 54.f - cnt1;
    const int col = tid*2;
    const float* base = (m==0)?L_in:(m==1)?A_in:V_in;
    float a0x=0.f,a0y=0.f,a1x=0.f,a1y=0.f;
    float b0x=0.f,b0y=0.f,b1x=0.f,b1y=0.f;
    for (int i=0;i<27;i++){
      float2 xa = *(const float2*)&base[(size_t)(d*54+i)*512 + col];
      float2 xb = *(const float2*)&base[(size_t)(d*54+i+27)*512 + col];
      if (spks[i])    { a1x+=xa.x; a1y+=xa.y; } else { a0x+=xa.x; a0y+=xa.y; }
      if (spks[i+27]) { b1x+=xb.x; b1y+=xb.y; } else { b0x+=xb.x; b0y+=xb.y; }
    }
    float s0x=a0x+b0x, s0y=a0y+b0y, s1x=a1x+b1x, s1y=a1y+b1y;
    if (m==0){
      float2 e0 = *(const float2*)&spk[col];
      float2 e1 = *(const float2*)&spk[512+col];
      s0x += cnt0*e0.x; s0y += cnt0*e0.y;
      s1x += cnt1*e1.x; s1y += cnt1*e1.y;
    }
    float2 o0; o0.x=s0x; o0.y=s0y;
    float2 o1; o1.x=s1x; o1.y=s1y;
    *(float2*)&FS[(size_t)(d*6+m*2  )*512 + col] = o0;
    *(float2*)&FS[(size_t)(d*6+m*2+1)*512 + col] = o1;
    if (m==0 && tid==0){ cnts[d*2]=cnt0; cnts[d*2+1]=cnt1; }
    return;
  }
  const int t = blockIdx.x - 48;       // 0..63: slot-0 tiles
  transpose_tile(tile, fc1, nullptr, WT, t>>3, t&7);
}

// ---------------------------------------------------------------------------
// fc1: blocks [0,324) X1 = feats @ fc1_W + b;
//      blocks [324,336) Gsum0 = FS @ fc1_W + cnt*b;
//      blocks [336,1104) transpose slots 4..15 (overlaps the GEMM)
// ---------------------------------------------------------------------------
__global__ __launch_bounds__(256) void fc1_kernel(
    const float* __restrict__ A_in, const float* __restrict__ V_in,
    const float* __restrict__ L_in, const float* __restrict__ qmask,
    const float* __restrict__ spk, const ushort_t* __restrict__ WTc,
    ushort_t* __restrict__ WT,
    const float* __restrict__ m0, const float* __restrict__ m1,
    const float* __restrict__ ms,
    const float* __restrict__ fc1_b, float* __restrict__ X1,
    const float* __restrict__ FS, const float* __restrict__ cnts,
    float* __restrict__ Gs)
{
  __shared__ __align__(16) union {
    ushort_t As[32*512];
    float tile[64][65];
  } sm;
  const int b = blockIdx.x, tid = threadIdx.x;
  const int wave = tid>>6, lane = tid&63;
  const int ml = lane&15, quad = lane>>4;
  if (b >= 336){
    const int bb = b - 336;            // 0..767 -> slots 4..15
    const int w = 4 + (bb>>6), t = bb&63;
    const float* src = (w<8)  ? m0 + (size_t)(w-4)*MATSZ
                     : (w<12) ? m1 + (size_t)(w-8)*MATSZ
                              : ms + (size_t)(w-12)*MATSZ;
    const float* src2 = (w>=12) ? m1 + (size_t)(w-12)*MATSZ : nullptr;
    transpose_tile(sm.tile, src, src2, WT + (size_t)w*MATSZ, t>>3, t&7);
    return;
  }
  if (b < 324){
    const int r0 = (b>>2)*32, col0 = (b&3)*128;
    {
      int row = tid>>3, seg = tid&7, gr = r0+row;
      int d = gr/162, rm = gr-d*162, m = rm/54, i = rm-m*54, t = d*54+i;
      const float* pa = ((m==0)?L_in:(m==1)?A_in:V_in) + (size_t)t*512 + seg*64;
      const float* pb = pa;
      bool hassp = (m==0);
      if (hassp){
        int sp = qmask[(i*16+d)*2+1] > qmask[(i*16+d)*2];
        pb = spk + sp*512 + seg*64;
      }
      int rsw = row&7;
      ushort_t* dstA = &sm.As[row*512 + seg*64];
      #pragma unroll
      for (int j=0;j<8;j++){
        f32x4 xa = *(const f32x4*)(pa+j*8), xb = *(const f32x4*)(pa+j*8+4);
        if (hassp){
          f32x4 ya = *(const f32x4*)(pb+j*8), yb = *(const f32x4*)(pb+j*8+4);
          #pragma unroll
          for (int jj=0;jj<4;jj++){ xa[jj]+=ya[jj]; xb[jj]+=yb[jj]; }
        }
        u16x8 v;
        #pragma unroll
        for (int jj=0;jj<4;jj++){ v[jj]=f2b(xa[jj]); v[4+jj]=f2b(xb[jj]); }
        *(u16x8*)&dstA[(j ^ rsw)<<3] = v;
      }
    }
    __syncthreads();
    f32x4 acc[2][2];
    gemm32(sm.As, WTc, col0, acc);
    #pragma unroll
    for (int nf=0;nf<2;nf++){
      int col = col0 + wave*32 + nf*16 + ml;
      float bv = fc1_b[col];
      #pragma unroll
      for (int mf=0;mf<2;mf++)
        #pragma unroll
        for (int r=0;r<4;r++){
          int gr = r0 + mf*16 + quad*4 + r;
          X1[(size_t)gr*512 + col] = acc[mf][nf][r] + bv;
        }
    }
  } else {
    const int bb = b-324;
    const int r0 = (bb>>2)*32, col0 = (bb&3)*128;
    stageA_flat(sm.As, FS, r0);
    __syncthreads();
    f32x4 acc[2][2];
    gemm32(sm.As, WTc, col0, acc);
    #pragma unroll
    for (int nf=0;nf<2;nf++){
      int col = col0 + wave*32 + nf*16 + ml;
      float bv = fc1_b[col];
      #pragma unroll
      for (int mf=0;mf<2;mf++)
        #pragma unroll
        for (int r=0;r<4;r++){
          int gr = r0 + mf*16 + quad*4 + r;   // < 96
          float cw = cnts[(gr/6)*2 + (gr&1)];
          Gs[(size_t)gr*512 + col] = acc[mf][nf][r] + cw*bv;
        }
    }
  }
}

// ---------------------------------------------------------------------------
// KA: blocks [0,324)   HS = gin@(Wself-INV53*W1)+m3_b   (gemm32)
//     blocks [324,348) Sp = Gs(96x512) @ [W0|W1]        (gemm32, wide)
//     blocks [348,1260) hyperedge aggregation into EB (2-way interleaved)
//     blocks [1260,1452) transpose slots 1..3 (launched only in D1)
// ---------------------------------------------------------------------------
__global__ __launch_bounds__(256) void ka_kernel(int kk,
    const float* __restrict__ gin, const float* __restrict__ Gs,
    const ushort_t* __restrict__ WT, const float* __restrict__ m3_b,
    float* __restrict__ HS, float* __restrict__ Sp,
    const float* __restrict__ edge_src, const float* __restrict__ ew_w,
    const int* __restrict__ het, const float* __restrict__ attr1,
    const float* __restrict__ attr2, float* __restrict__ EB,
    const float* __restrict__ hcW, ushort_t* __restrict__ WTmut)
{
  __shared__ __align__(16) union {
    ushort_t As[32*512];
    float tile[64][65];
  } sm;
  const int b = blockIdx.x, tid = threadIdx.x;
  const int wave = tid>>6, lane = tid&63;
  const int ml = lane&15, quad = lane>>4;
  if (b >= 1260){
    const int bb = b - 1260;           // 0..191 -> slots 1..3 (hc_W)
    const int w = 1 + (bb>>6), t = bb&63;
    transpose_tile(sm.tile, hcW + (size_t)(w-1)*MATSZ, nullptr,
                   WTmut + (size_t)w*MATSZ, t>>3, t&7);
    return;
  }
  if (b < 324){
    const int r0 = (b>>2)*32, col0 = (b&3)*128;
    stageA_flat(sm.As, gin, r0);
    __syncthreads();
    f32x4 acc[2][2];
    gemm32(sm.As, WT + (size_t)(12+kk)*MATSZ, col0, acc);
    #pragma unroll
    for (int nf=0;nf<2;nf++){
      int col = col0 + wave*32 + nf*16 + ml;
      float bv = m3_b[kk*512 + col];
      #pragma unroll
      for (int mf=0;mf<2;mf++)
        #pragma unroll
        for (int r=0;r<4;r++){
          int gr = r0 + mf*16 + quad*4 + r;
          HS[(size_t)gr*512 + col] = acc[mf][nf][r] + bv;
        }
    }
  } else if (b < 348){
    const int bb = b-324;
    const int rt = bb>>3, c8 = bb&7;
    const int r0 = rt*32, col0 = (c8&3)*128;
    const ushort_t* W = WT + (size_t)((c8<4 ? 4 : 8)+kk)*MATSZ;
    const int cb = (c8<4) ? 0 : 512;
    stageA_flat(sm.As, Gs, r0);
    __syncthreads();
    f32x4 acc[2][2];
    gemm32(sm.As, W, col0, acc);
    #pragma unroll
    for (int nf=0;nf<2;nf++){
      int col = cb + col0 + wave*32 + nf*16 + ml;
      #pragma unroll
      for (int mf=0;mf<2;mf++)
        #pragma unroll
        for (int r=0;r<4;r++){
          int row = r0 + mf*16 + quad*4 + r;   // < 96
          Sp[(size_t)row*1024 + col] = acc[mf][nf][r];
        }
    }
  } else {
    int e = b - 348;
    int d = e/57, r = e - d*57;
    int col = tid*2;
    float sx=0.f, sy=0.f, de=0.f;
    if (r < 3){
      // 2-way interleaved (i, i+27): doubles memory-level parallelism
      int nnz0 = d*324 + r*54;
      const float* row = edge_src + ((size_t)(d*162 + r*54))*512 + col;
      float sxa=0.f, sya=0.f, dea=0.f;
      float sxb=0.f, syb=0.f, deb=0.f;
      for (int i=0;i<27;i++){
        float wa = ew_w[nnz0+i];
        float wb = ew_w[nnz0+i+27];
        float2 xa = *(const float2*)(row + (size_t)i*512);
        float2 xb = *(const float2*)(row + (size_t)(i+27)*512);
        sxa += wa*xa.x; sya += wa*xa.y; dea += wa;
        sxb += wb*xb.x; syb += wb*xb.y; deb += wb;
      }
      sx = sxa+sxb; sy = sya+syb; de = dea+deb;
    } else {
      int i = r-3;
      int nnz0 = d*324 + 162 + i*3;
      #pragma unroll
      for (int m=0;m<3;m++){
        float w = ew_w[nnz0+m];
        const float* row = edge_src + ((size_t)(d*162 + m*54 + i))*512 + col;
        float2 x = *(const float2*)row;
        sx += w*x.x; sy += w*x.y; de += w;
      }
    }
    float invde = 1.0f/(de + 1e-8f);
    const float* at = het[e] ? attr1 : attr2;
    float2 o;
    o.x = sx*invde + at[col];
    o.y = sy*invde + at[col+1];
    *(float2*)(EB + (size_t)e*512 + col) = o;
  }
}

// ---------------------------------------------------------------------------
// KB: blocks [0,324) hg-GEMM out = relu(mix(EB)@W + b);
//     blocks [324,420) sf combine, 2-way interleaved (LAST: grid=96, all sf)
// ---------------------------------------------------------------------------
template<bool LAST>
__global__ __launch_bounds__(256) void kb_kernel(int lk,
    const float* __restrict__ EB, const ushort_t* __restrict__ WT,
    const float* __restrict__ hc_b, float* __restrict__ dst,
    const float* __restrict__ gin, const float* __restrict__ HS,
    const float* __restrict__ Sp, const float* __restrict__ qmask,
    const float* __restrict__ he_w,
    float* __restrict__ Gout, float* __restrict__ GsOut,
    const float* __restrict__ OUThg, float* __restrict__ dout,
    float* __restrict__ accp, unsigned int* __restrict__ counter)
{
  __shared__ __align__(16) union {
    ushort_t As[32*512];
    struct { unsigned char spks[54]; float red[256]; } sf;
  } sm;
  const int b = blockIdx.x, tid = threadIdx.x;
  if (!LAST && b < 324){
    const int r0 = (b>>2)*32, col0 = (b&3)*128;
    {
      int row = tid>>3, seg = tid&7, gr = r0+row;
      int d = gr/162, rm = gr-d*162, m = rm/54, i = rm-m*54;
      int em = d*57+m, eu = d*57+3+i;
      float w1 = he_w[em], w2 = he_w[eu], inv = 1.0f/(w1+w2+1e-8f);
      float c1 = w1*inv, c2 = w2*inv;
      const float* pa = EB + (size_t)em*512 + seg*64;
      const float* pb = EB + (size_t)eu*512 + seg*64;
      int rsw = row&7;
      ushort_t* dstA = &sm.As[row*512 + seg*64];
      #pragma unroll
      for (int j=0;j<8;j++){
        f32x4 xa = *(const f32x4*)(pa+j*8), xb = *(const f32x4*)(pa+j*8+4);
        f32x4 ya = *(const f32x4*)(pb+j*8), yb = *(const f32x4*)(pb+j*8+4);
        u16x8 v;
        #pragma unroll
        for (int jj=0;jj<4;jj++){
          v[jj]   = f2b(c1*xa[jj] + c2*ya[jj]);
          v[4+jj] = f2b(c1*xb[jj] + c2*yb[jj]);
        }
        *(u16x8*)&dstA[(j ^ rsw)<<3] = v;
      }
    }
    __syncthreads();
    f32x4 acc[2][2];
    gemm32(sm.As, WT + (size_t)(1+lk)*MATSZ, col0, acc);
    const int wave = tid>>6, lane = tid&63;
    const int ml = lane&15, quad = lane>>4;
    #pragma unroll
    for (int nf=0;nf<2;nf++){
      int col = col0 + wave*32 + nf*16 + ml;
      float bv = hc_b[lk*512 + col];
      #pragma unroll
      for (int mf=0;mf<2;mf++)
        #pragma unroll
        for (int r=0;r<4;r++){
          int gr = r0 + mf*16 + quad*4 + r;
          dst[(size_t)gr*512 + col] = fmaxf(acc[mf][nf][r] + bv, 0.f);
        }
    }
  } else {
    const int sfid = LAST ? b : b-324;
    const int g = sfid>>1, d = g/3;
    const int col = (sfid&1)*256 + tid;
    if (tid < 54)
      sm.sf.spks[tid] = qmask[(tid*16+d)*2+1] > qmask[(tid*16+d)*2];
    __syncthreads();
    const float* r0p = Sp + (size_t)(g*2)*1024;
    const float* r1p = Sp + (size_t)(g*2+1)*1024;
    float S1_0 = r0p[512+col];
    float S1_1 = r1p[512+col];
    float S0_0 = r1p[col];
    float S0_1 = r0p[col];
    size_t base = (size_t)g*54*512 + col;
    // 2-way interleaved (i, i+27)
    float gs0a=0.f, gs1a=0.f, sqa=0.f;
    float gs0b=0.f, gs1b=0.f, sqb=0.f;
    for (int i=0;i<27;i++){
      size_t offa = base + (size_t)i*512;
      size_t offb = base + (size_t)(i+27)*512;
      int spa = sm.sf.spks[i];
      int spb = sm.sf.spks[i+27];
      float hsa = HS[offa], gia = gin[offa];
      float hsb = HS[offb], gib = gin[offb];
      float S1a = spa ? S1_1 : S1_0, S0a = spa ? S0_1 : S0_0;
      float S1b = spb ? S1_1 : S1_0, S0b = spb ? S0_1 : S0_0;
      float fa = fmaxf((S1a + S0a)*INV53 + hsa, 0.f);
      float fb = fmaxf((S1b + S0b)*INV53 + hsb, 0.f);
      float gna = gia + fa;
      float gnb = gib + fb;
      if (LAST){
        sqa += fa*fa; sqb += fb*fb;
        dout[offa] = OUThg[offa] + gna;
        dout[offb] = OUThg[offb] + gnb;
      } else {
        Gout[offa] = gna;
        Gout[offb] = gnb;
        if (spa) gs1a += gna; else gs0a += gna;
        if (spb) gs1b += gnb; else gs0b += gnb;
      }
    }
    if (!LAST){
      GsOut[(size_t)(g*2)*512 + col]   = gs0a + gs0b;
      GsOut[(size_t)(g*2+1)*512 + col] = gs1a + gs1b;
    } else {
      sm.sf.red[tid] = sqa + sqb;
      __syncthreads();
      #pragma unroll
      for (int s=128; s>0; s>>=1){
        if (tid < s) sm.sf.red[tid] += sm.sf.red[tid+s];
        __syncthreads();
      }
      if (tid == 0){
        atomicAdd(accp, sm.sf.red[0]);
        __threadfence();
        unsigned int old = atomicAdd(counter, 1u);
        if (old == 95u)
          dout[(size_t)NNODE*512] = atomicAdd(accp, 0.0f) * (1.0f/1327104.0f);
      }
    }
  }
}

// ---------------------------------------------------------------------------
extern "C" void kernel_launch(void* const* d_in, const int* in_sizes, int n_in,
                              void* d_out, int out_size, void* d_ws, size_t ws_size,
                              hipStream_t stream)
{
  const float* A_in   = (const float*)d_in[0];
  const float* V_in   = (const float*)d_in[1];
  const float* L_in   = (const float*)d_in[2];
  const float* qmask  = (const float*)d_in[3];
  const float* spk    = (const float*)d_in[4];
  const float* fc1_W  = (const float*)d_in[5];
  const float* fc1_b  = (const float*)d_in[6];
  const float* he_w   = (const float*)d_in[7];
  const float* ew_w   = (const float*)d_in[8];
  const float* attr1  = (const float*)d_in[9];
  const float* attr2  = (const float*)d_in[10];
  const float* hc_W   = (const float*)d_in[11];
  const float* hc_b   = (const float*)d_in[12];
  const float* m3_W0  = (const float*)d_in[13];
  const float* m3_W1  = (const float*)d_in[14];
  const float* m3_Ws  = (const float*)d_in[15];
  const float* m3_b   = (const float*)d_in[16];
  const int*   het    = (const int*)d_in[18];
  float* dout = (float*)d_out;

  char* ws = (char*)d_ws;
  ushort_t* WT = (ushort_t*)ws;                       // 16 x 512KB bf16 = 8MB
  float* X1 = (float*)(ws + (size_t)16*MATSZ*2);
  float* OA = X1 + (size_t)NNODE*512;
  float* OB = OA + (size_t)NNODE*512;
  float* OC = OB + (size_t)NNODE*512;
  float* GA = OC + (size_t)NNODE*512;
  float* GB = GA + (size_t)NNODE*512;
  float* HS = GB + (size_t)NNODE*512;
  float* EB = HS + (size_t)NNODE*512;                 // 912*512
  float* Sp = EB + (size_t)912*512;                   // 96*1024
  float* Gs = Sp + 96*1024;                           // 96*512
  float* FS = Gs + 96*512;                            // 96*512
  float* cnts = FS + 96*512;                          // 32
  float* acc = cnts + 32;
  unsigned int* counter = (unsigned int*)(acc + 1);

  // D-1: FS + slot-0 transpose + init (only what fc1 needs)
  prep0_kernel<<<112,256,0,stream>>>(fc1_W, A_in, V_in, L_in, qmask, spk,
                                     WT, FS, cnts, acc, counter);
  // D0: fc1 GEMM + Gsum0 + transpose slots 4..15 (overlapped)
  fc1_kernel<<<1104,256,0,stream>>>(A_in, V_in, L_in, qmask, spk, WT, WT,
                                    m3_W0, m3_W1, m3_Ws, fc1_b,
                                    X1, FS, cnts, Gs);

  // D1: rgemm0 + Sp0 + edge0 + transpose slots 1..3 (overlapped)
  ka_kernel<<<1452,256,0,stream>>>(0, X1, Gs, WT, m3_b, HS, Sp,
                                   X1, ew_w, het, attr1, attr2, EB, hc_W, WT);
  // D2: hg0 + sf0 (sf emits Gs for next layer)
  kb_kernel<false><<<420,256,0,stream>>>(0, EB, WT, hc_b, OA, X1, HS, Sp,
      qmask, he_w, GA, Gs, nullptr, nullptr, acc, counter);
  // D3
  ka_kernel<<<1260,256,0,stream>>>(1, GA, Gs, WT, m3_b, HS, Sp,
                                   OA, ew_w, het, attr1, attr2, EB, hc_W, WT);
  // D4
  kb_kernel<false><<<420,256,0,stream>>>(1, EB, WT, hc_b, OB, GA, HS, Sp,
      qmask, he_w, GB, Gs, nullptr, nullptr, acc, counter);
  // D5
  ka_kernel<<<1260,256,0,stream>>>(2, GB, Gs, WT, m3_b, HS, Sp,
                                   OB, ew_w, het, attr1, attr2, EB, hc_W, WT);
  // D6
  kb_kernel<false><<<420,256,0,stream>>>(2, EB, WT, hc_b, OC, GB, HS, Sp,
      qmask, he_w, GA, Gs, nullptr, nullptr, acc, counter);
  // D7: rgemm3 + Sp3 only
  ka_kernel<<<348,256,0,stream>>>(3, GA, Gs, WT, m3_b, HS, Sp,
                                  X1, ew_w, het, attr1, attr2, EB, hc_W, WT);
  // D8: sf3 (LAST) -> dout + denoise scalar
  kb_kernel<true><<<96,256,0,stream>>>(3, EB, WT, hc_b, nullptr, GA, HS, Sp,
      qmask, he_w, nullptr, nullptr, OC, dout, acc, counter);

  (void)in_sizes; (void)n_in; (void)out_size; (void)ws_size;
}

// Round 13
// 251.114 us; speedup vs baseline: 1.0079x; 1.0079x over previous
//
#include <hip/hip_runtime.h>

typedef unsigned short ushort_t;
typedef __attribute__((ext_vector_type(4))) float f32x4;
typedef __attribute__((ext_vector_type(8))) short s16x8;
typedef __attribute__((ext_vector_type(8))) unsigned short u16x8;

#define NNODE 2592
#define MATSZ (512*512)
#define INV53 (1.0f/(53.0f + 1e-8f))

__device__ __forceinline__ ushort_t f2b(float f){
  union {unsigned int i; float f;} x; x.f = f;
  unsigned int r = (x.i + 0x7fffu + ((x.i>>16)&1u))>>16;
  return (ushort_t)r;
}

// ---------------------------------------------------------------------------
// gemm32 (verified): 32-row x 128-col tile, barrier-free K-loop.
// A in swizzled LDS (32x512 bf16); B streamed global->reg from WT[n][k].
// C/D: row = mf*16 + quad*4 + r, col = wave*32 + nf*16 + ml.
// ---------------------------------------------------------------------------
__device__ __forceinline__ void gemm32(const ushort_t* As,
    const ushort_t* W, int col0, f32x4 acc[2][2])
{
  const int tid = threadIdx.x;
  const int wave = tid>>6, lane = tid&63;
  const int ml = lane&15, quad = lane>>4;
  #pragma unroll
  for (int mf=0;mf<2;mf++)
    #pragma unroll
    for (int nf=0;nf<2;nf++) acc[mf][nf] = (f32x4){0.f,0.f,0.f,0.f};

  const ushort_t* bw0 = W + (size_t)(col0 + wave*32 + ml)*512 + quad*8;
  const ushort_t* bw1 = bw0 + (size_t)16*512;
  const int rsw = ml&7;
  #pragma unroll
  for (int ks=0; ks<16; ks++){
    const int chunk = ks*4 + quad;
    const int abase = (chunk>>3)*64 + (((chunk&7) ^ rsw)<<3);
    s16x8 a0 = *(const s16x8*)&As[(size_t)ml*512 + abase];
    s16x8 a1 = *(const s16x8*)&As[(size_t)(16+ml)*512 + abase];
    s16x8 b0 = *(const s16x8*)(bw0 + ks*32);
    s16x8 b1 = *(const s16x8*)(bw1 + ks*32);
    acc[0][0] = __builtin_amdgcn_mfma_f32_16x16x32_bf16(a0,b0,acc[0][0],0,0,0);
    acc[0][1] = __builtin_amdgcn_mfma_f32_16x16x32_bf16(a0,b1,acc[0][1],0,0,0);
    acc[1][0] = __builtin_amdgcn_mfma_f32_16x16x32_bf16(a1,b0,acc[1][0],0,0,0);
    acc[1][1] = __builtin_amdgcn_mfma_f32_16x16x32_bf16(a1,b1,acc[1][1],0,0,0);
  }
}

// stage 32 contiguous fp32 rows of a [*,512] matrix into swizzled bf16 LDS
__device__ __forceinline__ void stageA_flat(ushort_t* As, const float* src, int r0){
  const int tid = threadIdx.x;
  int row = tid>>3, seg = tid&7;
  const float* p = src + (size_t)(r0+row)*512 + seg*64;
  int rsw = row&7;
  ushort_t* dstA = &As[row*512 + seg*64];
  #pragma unroll
  for (int j=0;j<8;j++){
    f32x4 xa = *(const f32x4*)(p+j*8), xb = *(const f32x4*)(p+j*8+4);
    u16x8 v;
    #pragma unroll
    for (int jj=0;jj<4;jj++){ v[jj]=f2b(xa[jj]); v[4+jj]=f2b(xb[jj]); }
    *(u16x8*)&dstA[(j ^ rsw)<<3] = v;
  }
}

// vectorized 64x64 transpose tile: fp32 [k][n] -> bf16 dst[n][k]
__device__ __forceinline__ void transpose_tile(float (*tile)[65],
    const float* src, const float* src2, ushort_t* dst, int bx, int by)
{
  const int tid = threadIdx.x;
  int r0 = bx*64, c0 = by*64;
  #pragma unroll
  for (int j=0;j<4;j++){
    int idx = j*256 + tid;
    int r = idx>>4, c4 = (idx&15)*4;
    size_t off = (size_t)(r0+r)*512 + c0 + c4;
    f32x4 v = *(const f32x4*)&src[off];
    if (src2){
      f32x4 v2 = *(const f32x4*)&src2[off];
      #pragma unroll
      for (int jj=0;jj<4;jj++) v[jj] -= INV53 * v2[jj];
    }
    #pragma unroll
    for (int jj=0;jj<4;jj++) tile[r][c4+jj] = v[jj];
  }
  __syncthreads();
  #pragma unroll
  for (int j=0;j<2;j++){
    int idx = j*256 + tid;
    int c = idx>>3, r8 = (idx&7)*8;
    u16x8 v;
    #pragma unroll
    for (int tt=0;tt<8;tt++) v[tt] = f2b(tile[r8+tt][c]);
    *(u16x8*)&dst[(size_t)(c0+c)*512 + r0 + r8] = v;
  }
}

// slot -> fp32 source (slots 1..15)
__device__ __forceinline__ const float* slot_src(int w, const float* hcW,
    const float* m0w, const float* m1w, const float* msw){
  return (w<4)  ? hcW + (size_t)(w-1)*MATSZ
       : (w<8)  ? m0w + (size_t)(w-4)*MATSZ
       : (w<12) ? m1w + (size_t)(w-8)*MATSZ
                : msw + (size_t)(w-12)*MATSZ;
}

// ---------------------------------------------------------------------------
// prep0: blocks [0,48): FS[(d,m)] per-speaker feature sums (2-way interleave);
//        blocks [48,112): transpose slot 0 (fc1_W).  Block 0 inits acc/counter.
// ---------------------------------------------------------------------------
__global__ __launch_bounds__(256) void prep0_kernel(
    const float* __restrict__ fc1,
    const float* __restrict__ A_in, const float* __restrict__ V_in,
    const float* __restrict__ L_in, const float* __restrict__ qmask,
    const float* __restrict__ spk,
    ushort_t* __restrict__ WT, float* __restrict__ FS,
    float* __restrict__ cnts, float* __restrict__ acc,
    unsigned int* __restrict__ counter)
{
  __shared__ float tile[64][65];
  __shared__ unsigned char spks[54];
  const int tid = threadIdx.x;
  if (blockIdx.x < 48){
    if (blockIdx.x==0 && tid==0){ *acc = 0.f; *counter = 0u; }
    const int d = blockIdx.x/3, m = blockIdx.x - d*3;
    if (tid < 54)
      spks[tid] = qmask[(tid*16+d)*2+1] > qmask[(tid*16+d)*2];
    __syncthreads();
    float cnt1 = 0.f;
    #pragma unroll
    for (int i=0;i<54;i++) cnt1 += (float)spks[i];
    float cnt0 = 54.f - cnt1;
    const int col = tid*2;
    const float* base = (m==0)?L_in:(m==1)?A_in:V_in;
    float a0x=0.f,a0y=0.f,a1x=0.f,a1y=0.f;
    float b0x=0.f,b0y=0.f,b1x=0.f,b1y=0.f;
    for (int i=0;i<27;i++){
      float2 xa = *(const float2*)&base[(size_t)(d*54+i)*512 + col];
      float2 xb = *(const float2*)&base[(size_t)(d*54+i+27)*512 + col];
      if (spks[i])    { a1x+=xa.x; a1y+=xa.y; } else { a0x+=xa.x; a0y+=xa.y; }
      if (spks[i+27]) { b1x+=xb.x; b1y+=xb.y; } else { b0x+=xb.x; b0y+=xb.y; }
    }
    float s0x=a0x+b0x, s0y=a0y+b0y, s1x=a1x+b1x, s1y=a1y+b1y;
    if (m==0){
      float2 e0 = *(const float2*)&spk[col];
      float2 e1 = *(const float2*)&spk[512+col];
      s0x += cnt0*e0.x; s0y += cnt0*e0.y;
      s1x += cnt1*e1.x; s1y += cnt1*e1.y;
    }
    float2 o0; o0.x=s0x; o0.y=s0y;
    float2 o1; o1.x=s1x; o1.y=s1y;
    *(float2*)&FS[(size_t)(d*6+m*2  )*512 + col] = o0;
    *(float2*)&FS[(size_t)(d*6+m*2+1)*512 + col] = o1;
    if (m==0 && tid==0){ cnts[d*2]=cnt0; cnts[d*2+1]=cnt1; }
    return;
  }
  const int t = blockIdx.x - 48;       // 0..63: slot-0 tiles
  transpose_tile(tile, fc1, nullptr, WT, t>>3, t&7);
}

// ---------------------------------------------------------------------------
// fc1: blocks [0,324) X1 = feats @ fc1_W + b;
//      blocks [324,336) Gsum0 = FS @ fc1_W + cnt*b;
//      blocks [336,528) transpose slots {4,8,12} (kk=0, needed by D1)
// ---------------------------------------------------------------------------
__global__ __launch_bounds__(256) void fc1_kernel(
    const float* __restrict__ A_in, const float* __restrict__ V_in,
    const float* __restrict__ L_in, const float* __restrict__ qmask,
    const float* __restrict__ spk, const ushort_t* __restrict__ WTc,
    ushort_t* __restrict__ WT,
    const float* __restrict__ m0, const float* __restrict__ m1,
    const float* __restrict__ ms,
    const float* __restrict__ fc1_b, float* __restrict__ X1,
    const float* __restrict__ FS, const float* __restrict__ cnts,
    float* __restrict__ Gs)
{
  __shared__ __align__(16) union {
    ushort_t As[32*512];
    float tile[64][65];
  } sm;
  const int b = blockIdx.x, tid = threadIdx.x;
  const int wave = tid>>6, lane = tid&63;
  const int ml = lane&15, quad = lane>>4;
  if (b >= 336){
    const int bb = b - 336;            // 0..191 -> slots 4,8,12
    const int w = 4 + ((bb>>6)<<2), t = bb&63;
    const float* src = slot_src(w, nullptr, m0, m1, ms);
    const float* src2 = (w>=12) ? m1 + (size_t)(w-12)*MATSZ : nullptr;
    transpose_tile(sm.tile, src, src2, WT + (size_t)w*MATSZ, t>>3, t&7);
    return;
  }
  if (b < 324){
    const int r0 = (b>>2)*32, col0 = (b&3)*128;
    {
      int row = tid>>3, seg = tid&7, gr = r0+row;
      int d = gr/162, rm = gr-d*162, m = rm/54, i = rm-m*54, t = d*54+i;
      const float* pa = ((m==0)?L_in:(m==1)?A_in:V_in) + (size_t)t*512 + seg*64;
      const float* pb = pa;
      bool hassp = (m==0);
      if (hassp){
        int sp = qmask[(i*16+d)*2+1] > qmask[(i*16+d)*2];
        pb = spk + sp*512 + seg*64;
      }
      int rsw = row&7;
      ushort_t* dstA = &sm.As[row*512 + seg*64];
      #pragma unroll
      for (int j=0;j<8;j++){
        f32x4 xa = *(const f32x4*)(pa+j*8), xb = *(const f32x4*)(pa+j*8+4);
        if (hassp){
          f32x4 ya = *(const f32x4*)(pb+j*8), yb = *(const f32x4*)(pb+j*8+4);
          #pragma unroll
          for (int jj=0;jj<4;jj++){ xa[jj]+=ya[jj]; xb[jj]+=yb[jj]; }
        }
        u16x8 v;
        #pragma unroll
        for (int jj=0;jj<4;jj++){ v[jj]=f2b(xa[jj]); v[4+jj]=f2b(xb[jj]); }
        *(u16x8*)&dstA[(j ^ rsw)<<3] = v;
      }
    }
    __syncthreads();
    f32x4 acc[2][2];
    gemm32(sm.As, WTc, col0, acc);
    #pragma unroll
    for (int nf=0;nf<2;nf++){
      int col = col0 + wave*32 + nf*16 + ml;
      float bv = fc1_b[col];
      #pragma unroll
      for (int mf=0;mf<2;mf++)
        #pragma unroll
        for (int r=0;r<4;r++){
          int gr = r0 + mf*16 + quad*4 + r;
          X1[(size_t)gr*512 + col] = acc[mf][nf][r] + bv;
        }
    }
  } else {
    const int bb = b-324;
    const int r0 = (bb>>2)*32, col0 = (bb&3)*128;
    stageA_flat(sm.As, FS, r0);
    __syncthreads();
    f32x4 acc[2][2];
    gemm32(sm.As, WTc, col0, acc);
    #pragma unroll
    for (int nf=0;nf<2;nf++){
      int col = col0 + wave*32 + nf*16 + ml;
      float bv = fc1_b[col];
      #pragma unroll
      for (int mf=0;mf<2;mf++)
        #pragma unroll
        for (int r=0;r<4;r++){
          int gr = r0 + mf*16 + quad*4 + r;   // < 96
          float cw = cnts[(gr/6)*2 + (gr&1)];
          Gs[(size_t)gr*512 + col] = acc[mf][nf][r] + cw*bv;
        }
    }
  }
}

// ---------------------------------------------------------------------------
// KA: blocks [0,324)   HS = gin@(Wself-INV53*W1)+m3_b   (gemm32)
//     blocks [324,348) Sp = Gs(96x512) @ [W0|W1]        (gemm32, wide)
//     blocks [348,1260) hyperedge aggregation into EB (2-way interleaved)
//     blocks [1260,1324) transpose slot 1 (D1 only)
// ---------------------------------------------------------------------------
__global__ __launch_bounds__(256) void ka_kernel(int kk,
    const float* __restrict__ gin, const float* __restrict__ Gs,
    const ushort_t* __restrict__ WT, const float* __restrict__ m3_b,
    float* __restrict__ HS, float* __restrict__ Sp,
    const float* __restrict__ edge_src, const float* __restrict__ ew_w,
    const int* __restrict__ het, const float* __restrict__ attr1,
    const float* __restrict__ attr2, float* __restrict__ EB,
    const float* __restrict__ hcW, ushort_t* __restrict__ WTmut)
{
  __shared__ __align__(16) union {
    ushort_t As[32*512];
    float tile[64][65];
  } sm;
  const int b = blockIdx.x, tid = threadIdx.x;
  const int wave = tid>>6, lane = tid&63;
  const int ml = lane&15, quad = lane>>4;
  if (b >= 1260){
    const int bb = b - 1260;           // 0..63 -> slot 1 (hc_W layer 0)
    const int w = 1 + (bb>>6), t = bb&63;
    transpose_tile(sm.tile, hcW + (size_t)(w-1)*MATSZ, nullptr,
                   WTmut + (size_t)w*MATSZ, t>>3, t&7);
    return;
  }
  if (b < 324){
    const int r0 = (b>>2)*32, col0 = (b&3)*128;
    stageA_flat(sm.As, gin, r0);
    __syncthreads();
    f32x4 acc[2][2];
    gemm32(sm.As, WT + (size_t)(12+kk)*MATSZ, col0, acc);
    #pragma unroll
    for (int nf=0;nf<2;nf++){
      int col = col0 + wave*32 + nf*16 + ml;
      float bv = m3_b[kk*512 + col];
      #pragma unroll
      for (int mf=0;mf<2;mf++)
        #pragma unroll
        for (int r=0;r<4;r++){
          int gr = r0 + mf*16 + quad*4 + r;
          HS[(size_t)gr*512 + col] = acc[mf][nf][r] + bv;
        }
    }
  } else if (b < 348){
    const int bb = b-324;
    const int rt = bb>>3, c8 = bb&7;
    const int r0 = rt*32, col0 = (c8&3)*128;
    const ushort_t* W = WT + (size_t)((c8<4 ? 4 : 8)+kk)*MATSZ;
    const int cb = (c8<4) ? 0 : 512;
    stageA_flat(sm.As, Gs, r0);
    __syncthreads();
    f32x4 acc[2][2];
    gemm32(sm.As, W, col0, acc);
    #pragma unroll
    for (int nf=0;nf<2;nf++){
      int col = cb + col0 + wave*32 + nf*16 + ml;
      #pragma unroll
      for (int mf=0;mf<2;mf++)
        #pragma unroll
        for (int r=0;r<4;r++){
          int row = r0 + mf*16 + quad*4 + r;   // < 96
          Sp[(size_t)row*1024 + col] = acc[mf][nf][r];
        }
    }
  } else {
    int e = b - 348;
    int d = e/57, r = e - d*57;
    int col = tid*2;
    float sx=0.f, sy=0.f, de=0.f;
    if (r < 3){
      int nnz0 = d*324 + r*54;
      const float* row = edge_src + ((size_t)(d*162 + r*54))*512 + col;
      float sxa=0.f, sya=0.f, dea=0.f;
      float sxb=0.f, syb=0.f, deb=0.f;
      for (int i=0;i<27;i++){
        float wa = ew_w[nnz0+i];
        float wb = ew_w[nnz0+i+27];
        float2 xa = *(const float2*)(row + (size_t)i*512);
        float2 xb = *(const float2*)(row + (size_t)(i+27)*512);
        sxa += wa*xa.x; sya += wa*xa.y; dea += wa;
        sxb += wb*xb.x; syb += wb*xb.y; deb += wb;
      }
      sx = sxa+sxb; sy = sya+syb; de = dea+deb;
    } else {
      int i = r-3;
      int nnz0 = d*324 + 162 + i*3;
      #pragma unroll
      for (int m=0;m<3;m++){
        float w = ew_w[nnz0+m];
        const float* row = edge_src + ((size_t)(d*162 + m*54 + i))*512 + col;
        float2 x = *(const float2*)row;
        sx += w*x.x; sy += w*x.y; de += w;
      }
    }
    float invde = 1.0f/(de + 1e-8f);
    const float* at = het[e] ? attr1 : attr2;
    float2 o;
    o.x = sx*invde + at[col];
    o.y = sy*invde + at[col+1];
    *(float2*)(EB + (size_t)e*512 + col) = o;
  }
}

// ---------------------------------------------------------------------------
// KB: blocks [0,324) hg-GEMM out = relu(mix(EB)@W + b);
//     blocks [324,420) sf combine, 2-way interleaved;
//     blocks [420,...) transpose slots tsl.{x,y,z,w} (future layers' weights)
//     LAST: grid=96, sf only; dout + denoise scalar.
// ---------------------------------------------------------------------------
template<bool LAST>
__global__ __launch_bounds__(256) void kb_kernel(int lk,
    const float* __restrict__ EB, const ushort_t* __restrict__ WT,
    const float* __restrict__ hc_b, float* __restrict__ dst,
    const float* __restrict__ gin, const float* __restrict__ HS,
    const float* __restrict__ Sp, const float* __restrict__ qmask,
    const float* __restrict__ he_w,
    float* __restrict__ Gout, float* __restrict__ GsOut,
    const float* __restrict__ OUThg, float* __restrict__ dout,
    float* __restrict__ accp, unsigned int* __restrict__ counter,
    int4 tsl, const float* __restrict__ hcW, const float* __restrict__ m0w,
    const float* __restrict__ m1w, const float* __restrict__ msw,
    ushort_t* __restrict__ WTmut)
{
  __shared__ __align__(16) union {
    ushort_t As[32*512];
    float tile[64][65];
    struct { unsigned char spks[54]; float red[256]; } sf;
  } sm;
  const int b = blockIdx.x, tid = threadIdx.x;
  if (!LAST && b >= 420){
    const int bb = b - 420;
    const int wi = bb>>6, t = bb&63;
    const int w = (wi==0)?tsl.x:(wi==1)?tsl.y:(wi==2)?tsl.z:tsl.w;
    const float* src = slot_src(w, hcW, m0w, m1w, msw);
    const float* src2 = (w>=12) ? m1w + (size_t)(w-12)*MATSZ : nullptr;
    transpose_tile(sm.tile, src, src2, WTmut + (size_t)w*MATSZ, t>>3, t&7);
    return;
  }
  if (!LAST && b < 324){
    const int r0 = (b>>2)*32, col0 = (b&3)*128;
    {
      int row = tid>>3, seg = tid&7, gr = r0+row;
      int d = gr/162, rm = gr-d*162, m = rm/54, i = rm-m*54;
      int em = d*57+m, eu = d*57+3+i;
      float w1 = he_w[em], w2 = he_w[eu], inv = 1.0f/(w1+w2+1e-8f);
      float c1 = w1*inv, c2 = w2*inv;
      const float* pa = EB + (size_t)em*512 + seg*64;
      const float* pb = EB + (size_t)eu*512 + seg*64;
      int rsw = row&7;
      ushort_t* dstA = &sm.As[row*512 + seg*64];
      #pragma unroll
      for (int j=0;j<8;j++){
        f32x4 xa = *(const f32x4*)(pa+j*8), xb = *(const f32x4*)(pa+j*8+4);
        f32x4 ya = *(const f32x4*)(pb+j*8), yb = *(const f32x4*)(pb+j*8+4);
        u16x8 v;
        #pragma unroll
        for (int jj=0;jj<4;jj++){
          v[jj]   = f2b(c1*xa[jj] + c2*ya[jj]);
          v[4+jj] = f2b(c1*xb[jj] + c2*yb[jj]);
        }
        *(u16x8*)&dstA[(j ^ rsw)<<3] = v;
      }
    }
    __syncthreads();
    f32x4 acc[2][2];
    gemm32(sm.As, WT + (size_t)(1+lk)*MATSZ, col0, acc);
    const int wave = tid>>6, lane = tid&63;
    const int ml = lane&15, quad = lane>>4;
    #pragma unroll
    for (int nf=0;nf<2;nf++){
      int col = col0 + wave*32 + nf*16 + ml;
      float bv = hc_b[lk*512 + col];
      #pragma unroll
      for (int mf=0;mf<2;mf++)
        #pragma unroll
        for (int r=0;r<4;r++){
          int gr = r0 + mf*16 + quad*4 + r;
          dst[(size_t)gr*512 + col] = fmaxf(acc[mf][nf][r] + bv, 0.f);
        }
    }
  } else {
    const int sfid = LAST ? b : b-324;
    const int g = sfid>>1, d = g/3;
    const int col = (sfid&1)*256 + tid;
    if (tid < 54)
      sm.sf.spks[tid] = qmask[(tid*16+d)*2+1] > qmask[(tid*16+d)*2];
    __syncthreads();
    const float* r0p = Sp + (size_t)(g*2)*1024;
    const float* r1p = Sp + (size_t)(g*2+1)*1024;
    float S1_0 = r0p[512+col];
    float S1_1 = r1p[512+col];
    float S0_0 = r1p[col];
    float S0_1 = r0p[col];
    size_t base = (size_t)g*54*512 + col;
    float gs0a=0.f, gs1a=0.f, sqa=0.f;
    float gs0b=0.f, gs1b=0.f, sqb=0.f;
    for (int i=0;i<27;i++){
      size_t offa = base + (size_t)i*512;
      size_t offb = base + (size_t)(i+27)*512;
      int spa = sm.sf.spks[i];
      int spb = sm.sf.spks[i+27];
      float hsa = HS[offa], gia = gin[offa];
      float hsb = HS[offb], gib = gin[offb];
      float S1a = spa ? S1_1 : S1_0, S0a = spa ? S0_1 : S0_0;
      float S1b = spb ? S1_1 : S1_0, S0b = spb ? S0_1 : S0_0;
      float fa = fmaxf((S1a + S0a)*INV53 + hsa, 0.f);
      float fb = fmaxf((S1b + S0b)*INV53 + hsb, 0.f);
      float gna = gia + fa;
      float gnb = gib + fb;
      if (LAST){
        sqa += fa*fa; sqb += fb*fb;
        dout[offa] = OUThg[offa] + gna;
        dout[offb] = OUThg[offb] + gnb;
      } else {
        Gout[offa] = gna;
        Gout[offb] = gnb;
        if (spa) gs1a += gna; else gs0a += gna;
        if (spb) gs1b += gnb; else gs0b += gnb;
      }
    }
    if (!LAST){
      GsOut[(size_t)(g*2)*512 + col]   = gs0a + gs0b;
      GsOut[(size_t)(g*2+1)*512 + col] = gs1a + gs1b;
    } else {
      sm.sf.red[tid] = sqa + sqb;
      __syncthreads();
      #pragma unroll
      for (int s=128; s>0; s>>=1){
        if (tid < s) sm.sf.red[tid] += sm.sf.red[tid+s];
        __syncthreads();
      }
      if (tid == 0){
        atomicAdd(accp, sm.sf.red[0]);
        __threadfence();
        unsigned int old = atomicAdd(counter, 1u);
        if (old == 95u)
          dout[(size_t)NNODE*512] = atomicAdd(accp, 0.0f) * (1.0f/1327104.0f);
      }
    }
  }
}

// ---------------------------------------------------------------------------
extern "C" void kernel_launch(void* const* d_in, const int* in_sizes, int n_in,
                              void* d_out, int out_size, void* d_ws, size_t ws_size,
                              hipStream_t stream)
{
  const float* A_in   = (const float*)d_in[0];
  const float* V_in   = (const float*)d_in[1];
  const float* L_in   = (const float*)d_in[2];
  const float* qmask  = (const float*)d_in[3];
  const float* spk    = (const float*)d_in[4];
  const float* fc1_W  = (const float*)d_in[5];
  const float* fc1_b  = (const float*)d_in[6];
  const float* he_w   = (const float*)d_in[7];
  const float* ew_w   = (const float*)d_in[8];
  const float* attr1  = (const float*)d_in[9];
  const float* attr2  = (const float*)d_in[10];
  const float* hc_W   = (const float*)d_in[11];
  const float* hc_b   = (const float*)d_in[12];
  const float* m3_W0  = (const float*)d_in[13];
  const float* m3_W1  = (const float*)d_in[14];
  const float* m3_Ws  = (const float*)d_in[15];
  const float* m3_b   = (const float*)d_in[16];
  const int*   het    = (const int*)d_in[18];
  float* dout = (float*)d_out;

  char* ws = (char*)d_ws;
  ushort_t* WT = (ushort_t*)ws;                       // 16 x 512KB bf16 = 8MB
  float* X1 = (float*)(ws + (size_t)16*MATSZ*2);
  float* OA = X1 + (size_t)NNODE*512;
  float* OB = OA + (size_t)NNODE*512;
  float* OC = OB + (size_t)NNODE*512;
  float* GA = OC + (size_t)NNODE*512;
  float* GB = GA + (size_t)NNODE*512;
  float* HS = GB + (size_t)NNODE*512;
  float* EB = HS + (size_t)NNODE*512;                 // 912*512
  float* Sp = EB + (size_t)912*512;                   // 96*1024
  float* Gs = Sp + 96*1024;                           // 96*512
  float* FS = Gs + 96*512;                            // 96*512
  float* cnts = FS + 96*512;                          // 32
  float* acc = cnts + 32;
  unsigned int* counter = (unsigned int*)(acc + 1);

  const int4 tsl_d2 = make_int4(2, 5, 9, 13);   // hg1 + kk=1 slots (used D3/D4)
  const int4 tsl_d4 = make_int4(3, 6, 10, 14);  // hg2 + kk=2 slots (used D5/D6)
  const int4 tsl_d6 = make_int4(7, 11, 15, 0);  // kk=3 slots (used D7)
  const int4 tsl_nil = make_int4(0, 0, 0, 0);

  // D-1: FS + slot-0 transpose + init (only what fc1 needs)
  prep0_kernel<<<112,256,0,stream>>>(fc1_W, A_in, V_in, L_in, qmask, spk,
                                     WT, FS, cnts, acc, counter);
  // D0: fc1 GEMM + Gsum0 + transpose slots {4,8,12} (kk=0)
  fc1_kernel<<<528,256,0,stream>>>(A_in, V_in, L_in, qmask, spk, WT, WT,
                                   m3_W0, m3_W1, m3_Ws, fc1_b,
                                   X1, FS, cnts, Gs);

  // D1: rgemm0 + Sp0 + edge0 + transpose slot 1
  ka_kernel<<<1324,256,0,stream>>>(0, X1, Gs, WT, m3_b, HS, Sp,
                                   X1, ew_w, het, attr1, attr2, EB, hc_W, WT);
  // D2: hg0 + sf0 + transpose {2,5,9,13}
  kb_kernel<false><<<676,256,0,stream>>>(0, EB, WT, hc_b, OA, X1, HS, Sp,
      qmask, he_w, GA, Gs, nullptr, nullptr, acc, counter,
      tsl_d2, hc_W, m3_W0, m3_W1, m3_Ws, WT);
  // D3
  ka_kernel<<<1260,256,0,stream>>>(1, GA, Gs, WT, m3_b, HS, Sp,
                                   OA, ew_w, het, attr1, attr2, EB, hc_W, WT);
  // D4: hg1 + sf1 + transpose {3,6,10,14}
  kb_kernel<false><<<676,256,0,stream>>>(1, EB, WT, hc_b, OB, GA, HS, Sp,
      qmask, he_w, GB, Gs, nullptr, nullptr, acc, counter,
      tsl_d4, hc_W, m3_W0, m3_W1, m3_Ws, WT);
  // D5
  ka_kernel<<<1260,256,0,stream>>>(2, GB, Gs, WT, m3_b, HS, Sp,
                                   OB, ew_w, het, attr1, attr2, EB, hc_W, WT);
  // D6: hg2 + sf2 + transpose {7,11,15}
  kb_kernel<false><<<612,256,0,stream>>>(2, EB, WT, hc_b, OC, GB, HS, Sp,
      qmask, he_w, GA, Gs, nullptr, nullptr, acc, counter,
      tsl_d6, hc_W, m3_W0, m3_W1, m3_Ws, WT);
  // D7: rgemm3 + Sp3 only
  ka_kernel<<<348,256,0,stream>>>(3, GA, Gs, WT, m3_b, HS, Sp,
                                  X1, ew_w, het, attr1, attr2, EB, hc_W, WT);
  // D8: sf3 (LAST) -> dout + denoise scalar
  kb_kernel<true><<<96,256,0,stream>>>(3, EB, WT, hc_b, nullptr, GA, HS, Sp,
      qmask, he_w, nullptr, nullptr, OC, dout, acc, counter,
      tsl_nil, nullptr, nullptr, nullptr, nullptr, nullptr);

  (void)in_sizes; (void)n_in; (void)out_size; (void)ws_size;
}